// Round 2
// baseline (141.837 us; speedup 1.0000x reference)
//
#include <hip/hip_runtime.h>

typedef unsigned short u16;
typedef __attribute__((ext_vector_type(4))) float f32x4;
typedef __attribute__((ext_vector_type(8))) short s16x8;

#define BM 128
#define BN 128
#define BK 32

__device__ inline float bf2f(u16 u) {
    unsigned v = ((unsigned)u) << 16;
    return __builtin_bit_cast(float, v);
}
__device__ inline u16 f2bf(float f) {
    unsigned u = __builtin_bit_cast(unsigned, f);
    unsigned r = (u + 0x7FFFu + ((u >> 16) & 1u)) >> 16;
    return (u16)r;
}

typedef const __attribute__((address_space(1))) void* gptr_t;
typedef __attribute__((address_space(3))) void* lptr_t;
__device__ inline void gload16(const u16* gp, u16* lp) {
    __builtin_amdgcn_global_load_lds((gptr_t)gp, (lptr_t)lp, 16, 0, 0);
}

// ---------------- K0: x f32 [8][256][6400] -> xT bf16 [8][6400][256] ----------------
__global__ __launch_bounds__(256) void transpose_x(const float* __restrict__ x,
                                                   u16* __restrict__ xT) {
    int blk = blockIdx.x;              // 800 = 8 * 100
    int b = blk / 100, hw0 = (blk % 100) * 64;
    int t = threadIdx.x;
    int hw = hw0 + (t & 63);
    const float* xb = x + (size_t)b * 256 * 6400;
    u16* xtb = xT + ((size_t)b * 6400 + hw) * 256;
    for (int oct = (t >> 6); oct < 32; oct += 4) {
        int c0 = oct * 8;
        union { u16 s[8]; int4 q; } u;
#pragma unroll
        for (int j = 0; j < 8; ++j) u.s[j] = f2bf(xb[(size_t)(c0 + j) * 6400 + hw]);
        *(int4*)(xtb + c0) = u.q;
    }
}

// ---------------- prep: f32 weights -> bf16 (permuted) + f32 fused biases ----------------
__global__ __launch_bounds__(256) void prep(
    const float* __restrict__ stem_w,
    const float* __restrict__ cls_conv_w, const float* __restrict__ cls_conv_b,
    const float* __restrict__ reg_conv_w, const float* __restrict__ reg_conv_b,
    const float* __restrict__ cls_pred_w, const float* __restrict__ cls_pred_b,
    const float* __restrict__ reg_pred_w, const float* __restrict__ reg_pred_b,
    const float* __restrict__ obj_pred_w, const float* __restrict__ obj_pred_b,
    u16* __restrict__ Wsb, u16* __restrict__ Wc, u16* __restrict__ Wf,
    float* __restrict__ bc, float* __restrict__ bp) {
    int i0 = blockIdx.x * 256 + threadIdx.x;
    int stride = gridDim.x * 256;
    // Wsb [256][256] <- stem_w (same layout)
    for (int i = i0; i < 256 * 256; i += stride) Wsb[i] = f2bf(stem_w[i]);
    // Wc [512][2304] with k' = j*256 + c  <-  conv_w[o][c*9 + j]
    for (int i = i0; i < 512 * 2304; i += stride) {
        int o = i / 2304, kk = i % 2304;
        int j = kk >> 8, c = kk & 255;
        const float* src = (o < 256) ? (cls_conv_w + (size_t)o * 2304)
                                     : (reg_conv_w + (size_t)(o - 256) * 2304);
        Wc[i] = f2bf(src[c * 9 + j]);
    }
    // Wf [128][512]: rows 0-3 reg_pred (k 256..511), 4 obj, 5-84 cls (k 0..255), rest 0
    for (int i = i0; i < 128 * 512; i += stride) {
        int o = i >> 9, k = i & 511;
        float v = 0.f;
        if (o < 4)       { if (k >= 256) v = reg_pred_w[o * 256 + (k - 256)]; }
        else if (o == 4) { if (k >= 256) v = obj_pred_w[k - 256]; }
        else if (o < 85) { if (k < 256)  v = cls_pred_w[(o - 5) * 256 + k]; }
        Wf[i] = f2bf(v);
    }
    for (int i = i0; i < 512; i += stride)
        bc[i] = (i < 256) ? cls_conv_b[i] : reg_conv_b[i - 256];
    for (int i = i0; i < 128; i += stride) {
        float v = 0.f;
        if (i < 4) v = reg_pred_b[i];
        else if (i == 4) v = obj_pred_b[0];
        else if (i < 85) v = cls_pred_b[i - 5];
        bp[i] = v;
    }
}

// ---------------- K2: gather pf'[n][j*256+c] from NHWC bf16 stem ----------------
__global__ __launch_bounds__(256) void gather(const u16* __restrict__ stem,
                                              const int* __restrict__ idx,
                                              u16* __restrict__ pf) {
    int t = threadIdx.x;
    int seg = blockIdx.x * 8 + (t >> 5);   // 147456 segments
    int n = seg / 9, j = seg % 9;
    int b = idx[n * 3 + 0], y = idx[n * 3 + 1], x = idx[n * 3 + 2];
    int yy = y + j / 3 - 1;
    int xx = x + j % 3 - 1;
    int tl = t & 31;
    int4 v = make_int4(0, 0, 0, 0);
    if ((unsigned)yy < 80u && (unsigned)xx < 80u) {
        const u16* src = stem + ((size_t)(b * 6400 + yy * 80 + xx)) * 256 + tl * 8;
        v = *(const int4*)src;
    }
    *(int4*)(pf + (size_t)n * 2304 + j * 256 + tl * 8) = v;
}

// ---------------- gemm_bt: D[m,n] = epi(sum_k A[m,k]*B[n,k] + bias[n]) ----------------
// EPI 0: silu, bf16 store, ldd = N.  EPI 1: plain, f32 store, only cols < storeN, ldd = storeN.
template <int EPI>
__global__ __launch_bounds__(256, 2) void gemm_bt(
    const u16* __restrict__ A, const u16* __restrict__ B,
    const float* __restrict__ bias, void* __restrict__ Dv,
    int K, int ldd, int storeN) {
    __shared__ __align__(16) u16 lA[BM * BK];
    __shared__ __align__(16) u16 lB[BN * BK];
    const int tid = threadIdx.x;
    const int lane = tid & 63;
    const int wid = tid >> 6;
    const int wm = wid >> 1, wn = wid & 1;
    const int m0 = blockIdx.x * BM;
    const int n0 = blockIdx.y * BN;

    const int srow = lane >> 2;        // 0..15 (staging row within 16-row chunk)
    const int scol = (lane & 3) * 8;   // staging col (elements)
    const int arow = lane & 15;
    const int khalf = (lane >> 4) * 8;

    f32x4 acc[4][4] = {};

    for (int k0 = 0; k0 < K; k0 += BK) {
#pragma unroll
        for (int r = 0; r < 2; ++r) {
            int row = r * 64 + wid * 16 + srow;
            gload16(A + (size_t)(m0 + row) * K + k0 + scol, lA + r * 2048 + wid * 512);
            gload16(B + (size_t)(n0 + row) * K + k0 + scol, lB + r * 2048 + wid * 512);
        }
        __syncthreads();
        s16x8 af[4], bfr[4];
#pragma unroll
        for (int f = 0; f < 4; ++f) {
            af[f]  = *(const s16x8*)&lA[(wm * 64 + f * 16 + arow) * BK + khalf];
            bfr[f] = *(const s16x8*)&lB[(wn * 64 + f * 16 + arow) * BK + khalf];
        }
#pragma unroll
        for (int i = 0; i < 4; ++i)
#pragma unroll
            for (int j = 0; j < 4; ++j)
                acc[i][j] = __builtin_amdgcn_mfma_f32_16x16x32_bf16(af[i], bfr[j],
                                                                    acc[i][j], 0, 0, 0);
        __syncthreads();
    }

#pragma unroll
    for (int i = 0; i < 4; ++i) {
        int gr0 = m0 + wm * 64 + i * 16 + (lane >> 4) * 4;
#pragma unroll
        for (int j = 0; j < 4; ++j) {
            int gc = n0 + wn * 64 + j * 16 + (lane & 15);
            if (EPI == 1 && gc >= storeN) continue;
            float bb = bias[gc];
#pragma unroll
            for (int r = 0; r < 4; ++r) {
                float v = acc[i][j][r] + bb;
                if (EPI == 0) {
                    v = v / (1.0f + __expf(-v));
                    ((u16*)Dv)[(size_t)(gr0 + r) * ldd + gc] = f2bf(v);
                } else {
                    ((float*)Dv)[(size_t)(gr0 + r) * ldd + gc] = v;
                }
            }
        }
    }
}

extern "C" void kernel_launch(void* const* d_in, const int* in_sizes, int n_in,
                              void* d_out, int out_size, void* d_ws, size_t ws_size,
                              hipStream_t stream) {
    const float* x          = (const float*)d_in[0];
    const int*   idx        = (const int*)d_in[1];
    const float* stem_w     = (const float*)d_in[2];
    const float* stem_b     = (const float*)d_in[3];
    const float* cls_conv_w = (const float*)d_in[4];
    const float* cls_conv_b = (const float*)d_in[5];
    const float* reg_conv_w = (const float*)d_in[6];
    const float* reg_conv_b = (const float*)d_in[7];
    const float* cls_pred_w = (const float*)d_in[8];
    const float* cls_pred_b = (const float*)d_in[9];
    const float* reg_pred_w = (const float*)d_in[10];
    const float* reg_pred_b = (const float*)d_in[11];
    const float* obj_pred_w = (const float*)d_in[12];
    const float* obj_pred_b = (const float*)d_in[13];
    float* out = (float*)d_out;
    char* ws = (char*)d_ws;

    // ws layout (bytes); total ~147.3 MB
    u16*  xT    = (u16*)(ws);                    // 8*6400*256*2   = 26,214,400
    u16*  stem  = (u16*)(ws + 26214400);         // 26,214,400 (NHWC bf16)
    u16*  pf    = (u16*)(ws + 52428800);         // 16384*2304*2   = 75,497,472
    u16*  feat  = (u16*)(ws + 127926272);        // 16384*512*2    = 16,777,216
    u16*  Wc    = (u16*)(ws + 144703488);        // 512*2304*2     = 2,359,296
    u16*  Wf    = (u16*)(ws + 147062784);        // 128*512*2      = 131,072
    u16*  Wsb   = (u16*)(ws + 147193856);        // 256*256*2      = 131,072
    float* bc   = (float*)(ws + 147324928);      // 2048
    float* bp   = (float*)(ws + 147326976);      // 512

    prep<<<1024, 256, 0, stream>>>(stem_w,
                                   cls_conv_w, cls_conv_b, reg_conv_w, reg_conv_b,
                                   cls_pred_w, cls_pred_b, reg_pred_w, reg_pred_b,
                                   obj_pred_w, obj_pred_b,
                                   Wsb, Wc, Wf, bc, bp);
    transpose_x<<<800, 256, 0, stream>>>(x, xT);
    // K1: stem = silu(xT @ stem_w^T + b)  -> NHWC bf16 [51200][256]
    gemm_bt<0><<<dim3(400, 2), 256, 0, stream>>>(xT, Wsb, stem_b, stem, 256, 256, 256);
    gather<<<18432, 256, 0, stream>>>(stem, idx, pf);
    // K3: feat = silu(pf @ Wc^T + bc)  [16384][512] (cls | reg)
    gemm_bt<0><<<dim3(128, 4), 256, 0, stream>>>(pf, Wc, bc, feat, 2304, 512, 512);
    // K4: out[n][p<85] = feat @ Wf^T + bp  (f32 store)
    gemm_bt<1><<<dim3(128, 1), 256, 0, stream>>>(feat, Wf, bp, out, 512, 85, 85);
}

// Round 3
// 121.924 us; speedup vs baseline: 1.1633x; 1.1633x over previous
//
#include <hip/hip_runtime.h>

typedef unsigned short u16;
typedef __attribute__((ext_vector_type(4))) float f32x4;
typedef __attribute__((ext_vector_type(8))) short s16x8;

#define BM 128
#define BN 128
#define BK 32

__device__ inline float bf2f(u16 u) {
    unsigned v = ((unsigned)u) << 16;
    return __builtin_bit_cast(float, v);
}
__device__ inline u16 f2bf(float f) {
    unsigned u = __builtin_bit_cast(unsigned, f);
    unsigned r = (u + 0x7FFFu + ((u >> 16) & 1u)) >> 16;
    return (u16)r;
}

typedef const __attribute__((address_space(1))) void* gptr_t;
typedef __attribute__((address_space(3))) void* lptr_t;
__device__ inline void gload16(const u16* gp, u16* lp) {
    __builtin_amdgcn_global_load_lds((gptr_t)gp, (lptr_t)lp, 16, 0, 0);
}

// ---------------- K0: x f32 [8][256][6400] -> xT bf16 [8][6400][256] ----------------
__global__ __launch_bounds__(256) void transpose_x(const float* __restrict__ x,
                                                   u16* __restrict__ xT) {
    int blk = blockIdx.x;              // 800 = 8 * 100
    int b = blk / 100, hw0 = (blk % 100) * 64;
    int t = threadIdx.x;
    int hw = hw0 + (t & 63);
    const float* xb = x + (size_t)b * 256 * 6400;
    u16* xtb = xT + ((size_t)b * 6400 + hw) * 256;
    for (int oct = (t >> 6); oct < 32; oct += 4) {
        int c0 = oct * 8;
        union { u16 s[8]; int4 q; } u;
#pragma unroll
        for (int j = 0; j < 8; ++j) u.s[j] = f2bf(xb[(size_t)(c0 + j) * 6400 + hw]);
        *(int4*)(xtb + c0) = u.q;
    }
}

// ---------------- prep: f32 weights -> bf16 (permuted) + f32 fused biases ----------------
__global__ __launch_bounds__(256) void prep(
    const float* __restrict__ stem_w,
    const float* __restrict__ cls_conv_w, const float* __restrict__ cls_conv_b,
    const float* __restrict__ reg_conv_w, const float* __restrict__ reg_conv_b,
    const float* __restrict__ cls_pred_w, const float* __restrict__ cls_pred_b,
    const float* __restrict__ reg_pred_w, const float* __restrict__ reg_pred_b,
    const float* __restrict__ obj_pred_w, const float* __restrict__ obj_pred_b,
    u16* __restrict__ Wsb, u16* __restrict__ Wc, u16* __restrict__ Wf,
    float* __restrict__ bc, float* __restrict__ bp, u16* __restrict__ zpage) {
    int i0 = blockIdx.x * 256 + threadIdx.x;
    int stride = gridDim.x * 256;
    // Wsb [256][256] <- stem_w (same layout)
    for (int i = i0; i < 256 * 256; i += stride) Wsb[i] = f2bf(stem_w[i]);
    // Wc [512][2304] with k' = j*256 + c  <-  conv_w[o][c*9 + j]
    for (int i = i0; i < 512 * 2304; i += stride) {
        int o = i / 2304, kk = i % 2304;
        int j = kk >> 8, c = kk & 255;
        const float* src = (o < 256) ? (cls_conv_w + (size_t)o * 2304)
                                     : (reg_conv_w + (size_t)(o - 256) * 2304);
        Wc[i] = f2bf(src[c * 9 + j]);
    }
    // Wf [128][512]: rows 0-3 reg_pred (k 256..511), 4 obj, 5-84 cls (k 0..255), rest 0
    for (int i = i0; i < 128 * 512; i += stride) {
        int o = i >> 9, k = i & 511;
        float v = 0.f;
        if (o < 4)       { if (k >= 256) v = reg_pred_w[o * 256 + (k - 256)]; }
        else if (o == 4) { if (k >= 256) v = obj_pred_w[k - 256]; }
        else if (o < 85) { if (k < 256)  v = cls_pred_w[(o - 5) * 256 + k]; }
        Wf[i] = f2bf(v);
    }
    for (int i = i0; i < 512; i += stride)
        bc[i] = (i < 256) ? cls_conv_b[i] : reg_conv_b[i - 256];
    for (int i = i0; i < 128; i += stride) {
        float v = 0.f;
        if (i < 4) v = reg_pred_b[i];
        else if (i == 4) v = obj_pred_b[0];
        else if (i < 85) v = cls_pred_b[i - 5];
        bp[i] = v;
    }
    for (int i = i0; i < 256; i += stride) zpage[i] = 0;
}

// ---------------- rowoff: per (n, j) element offset into NHWC stem, or -1 ----------------
__global__ __launch_bounds__(256) void rowptr_prep(const int* __restrict__ idx,
                                                   int* __restrict__ rowoff) {
    int i = blockIdx.x * 256 + threadIdx.x;       // 147456 = 16384*9
    if (i >= 16384 * 9) return;
    int n = i / 9, j = i % 9;
    int b = idx[n * 3 + 0], y = idx[n * 3 + 1], x = idx[n * 3 + 2];
    int yy = y + j / 3 - 1;
    int xx = x + j % 3 - 1;
    rowoff[i] = ((unsigned)yy < 80u && (unsigned)xx < 80u)
                    ? (b * 6400 + yy * 80 + xx) * 256 : -1;
}

// ---------------- gemm_bt (verified): D[m,n] = epi(sum_k A[m,k]*B[n,k] + bias[n]) ----------
// EPI 0: silu, bf16 store, ldd = N.  EPI 1: plain, f32 store, only cols < storeN, ldd = storeN.
template <int EPI>
__global__ __launch_bounds__(256, 2) void gemm_bt(
    const u16* __restrict__ A, const u16* __restrict__ B,
    const float* __restrict__ bias, void* __restrict__ Dv,
    int K, int ldd, int storeN) {
    __shared__ __align__(16) u16 lA[BM * BK];
    __shared__ __align__(16) u16 lB[BN * BK];
    const int tid = threadIdx.x;
    const int lane = tid & 63;
    const int wid = tid >> 6;
    const int wm = wid >> 1, wn = wid & 1;
    const int m0 = blockIdx.x * BM;
    const int n0 = blockIdx.y * BN;

    const int srow = lane >> 2;        // 0..15 (staging row within 16-row chunk)
    const int scol = (lane & 3) * 8;   // staging col (elements)
    const int arow = lane & 15;
    const int khalf = (lane >> 4) * 8;

    f32x4 acc[4][4] = {};

    for (int k0 = 0; k0 < K; k0 += BK) {
#pragma unroll
        for (int r = 0; r < 2; ++r) {
            int row = r * 64 + wid * 16 + srow;
            gload16(A + (size_t)(m0 + row) * K + k0 + scol, lA + r * 2048 + wid * 512);
            gload16(B + (size_t)(n0 + row) * K + k0 + scol, lB + r * 2048 + wid * 512);
        }
        __syncthreads();
        s16x8 af[4], bfr[4];
#pragma unroll
        for (int f = 0; f < 4; ++f) {
            af[f]  = *(const s16x8*)&lA[(wm * 64 + f * 16 + arow) * BK + khalf];
            bfr[f] = *(const s16x8*)&lB[(wn * 64 + f * 16 + arow) * BK + khalf];
        }
#pragma unroll
        for (int i = 0; i < 4; ++i)
#pragma unroll
            for (int j = 0; j < 4; ++j)
                acc[i][j] = __builtin_amdgcn_mfma_f32_16x16x32_bf16(af[i], bfr[j],
                                                                    acc[i][j], 0, 0, 0);
        __syncthreads();
    }

#pragma unroll
    for (int i = 0; i < 4; ++i) {
        int gr0 = m0 + wm * 64 + i * 16 + (lane >> 4) * 4;
#pragma unroll
        for (int j = 0; j < 4; ++j) {
            int gc = n0 + wn * 64 + j * 16 + (lane & 15);
            if (EPI == 1 && gc >= storeN) continue;
            float bb = bias[gc];
#pragma unroll
            for (int r = 0; r < 4; ++r) {
                float v = acc[i][j][r] + bb;
                if (EPI == 0) {
                    v = v / (1.0f + __expf(-v));
                    ((u16*)Dv)[(size_t)(gr0 + r) * ldd + gc] = f2bf(v);
                } else {
                    ((float*)Dv)[(size_t)(gr0 + r) * ldd + gc] = v;
                }
            }
        }
    }
}

// ---------------- K3 fused: feat = silu( gather(stem)[m,:] @ Wc^T + bc ) ----------------
// A rows gathered from NHWC stem via rowoff (element offset or -1 -> zero page).
// BK=64, chunk XOR-swizzle (rule 21: linear LDS dest, inverse-swz per-lane SOURCE, swz READ).
__global__ __launch_bounds__(256, 2) void gemm_conv(
    const u16* __restrict__ stem, const int* __restrict__ rowoff,
    const u16* __restrict__ zpage, const u16* __restrict__ B,
    const float* __restrict__ bias, u16* __restrict__ D) {
    __shared__ __align__(16) u16 lA[128 * 64];
    __shared__ __align__(16) u16 lB[128 * 64];
    const int tid = threadIdx.x;
    const int lane = tid & 63;
    const int wid = tid >> 6;
    const int wm = wid >> 1, wn = wid & 1;
    const int m0 = blockIdx.x * 128;
    const int n0 = blockIdx.y * 128;

    const int srw = lane >> 3;          // staging row within 8-row group (= row&7)
    const int cc  = lane & 7;           // staging chunk slot (16B units)
    const int arow = lane & 15;
    const int khi  = lane >> 4;         // 0..3, k-subchunk within 32

    f32x4 acc[4][4] = {};

    for (int k0 = 0; k0 < 2304; k0 += 64) {
        const int j  = k0 >> 8;         // kernel tap 0..8 (single tap per 64-strip)
        const int c0 = k0 & 255;        // channel base within tap
#pragma unroll
        for (int r = 0; r < 4; ++r) {
            int row = r * 32 + wid * 8 + srw;          // 0..127 ; row&7 == srw
            int gch = (cc ^ srw) * 8;                  // inverse-swizzled source chunk
            int roff = rowoff[(m0 + row) * 9 + j];
            const u16* srcA = (roff < 0) ? (zpage + gch)
                                         : (stem + roff + c0 + gch);
            gload16(srcA, lA + (r * 32 + wid * 8) * 64);
            gload16(B + (size_t)(n0 + row) * 2304 + k0 + gch,
                    lB + (r * 32 + wid * 8) * 64);
        }
        __syncthreads();
        s16x8 af[2][4], bfr[2][4];
#pragma unroll
        for (int f = 0; f < 4; ++f) {
            int sa = arow & 7;
            int ra = (wm * 64 + f * 16 + arow) * 64;
            int rb = (wn * 64 + f * 16 + arow) * 64;
#pragma unroll
            for (int ks = 0; ks < 2; ++ks) {
                int q = ks * 4 + khi;                  // logical chunk 0..7
                af[ks][f]  = *(const s16x8*)&lA[ra + ((q ^ sa) << 3)];
                bfr[ks][f] = *(const s16x8*)&lB[rb + ((q ^ sa) << 3)];
            }
        }
#pragma unroll
        for (int ks = 0; ks < 2; ++ks)
#pragma unroll
            for (int i = 0; i < 4; ++i)
#pragma unroll
                for (int jj = 0; jj < 4; ++jj)
                    acc[i][jj] = __builtin_amdgcn_mfma_f32_16x16x32_bf16(
                        af[ks][i], bfr[ks][jj], acc[i][jj], 0, 0, 0);
        __syncthreads();
    }

#pragma unroll
    for (int i = 0; i < 4; ++i) {
        int gr0 = m0 + wm * 64 + i * 16 + khi * 4;
#pragma unroll
        for (int jj = 0; jj < 4; ++jj) {
            int gc = n0 + wn * 64 + jj * 16 + arow;
            float bb = bias[gc];
#pragma unroll
            for (int r = 0; r < 4; ++r) {
                float v = acc[i][jj][r] + bb;
                v = v / (1.0f + __expf(-v));
                D[(size_t)(gr0 + r) * 512 + gc] = f2bf(v);
            }
        }
    }
}

extern "C" void kernel_launch(void* const* d_in, const int* in_sizes, int n_in,
                              void* d_out, int out_size, void* d_ws, size_t ws_size,
                              hipStream_t stream) {
    const float* x          = (const float*)d_in[0];
    const int*   idx        = (const int*)d_in[1];
    const float* stem_w     = (const float*)d_in[2];
    const float* stem_b     = (const float*)d_in[3];
    const float* cls_conv_w = (const float*)d_in[4];
    const float* cls_conv_b = (const float*)d_in[5];
    const float* reg_conv_w = (const float*)d_in[6];
    const float* reg_conv_b = (const float*)d_in[7];
    const float* cls_pred_w = (const float*)d_in[8];
    const float* cls_pred_b = (const float*)d_in[9];
    const float* reg_pred_w = (const float*)d_in[10];
    const float* reg_pred_b = (const float*)d_in[11];
    const float* obj_pred_w = (const float*)d_in[12];
    const float* obj_pred_b = (const float*)d_in[13];
    float* out = (float*)d_out;
    char* ws = (char*)d_ws;

    // ws layout (bytes), all 16B-aligned; total ~72.4 MB
    u16*  xT     = (u16*)(ws);                    // 8*6400*256*2  = 26,214,400
    u16*  stem   = (u16*)(ws + 26214400);         // 26,214,400 (NHWC bf16)
    u16*  feat   = (u16*)(ws + 52428800);         // 16384*512*2   = 16,777,216
    u16*  Wc     = (u16*)(ws + 69206016);         // 512*2304*2    = 2,359,296
    u16*  Wf     = (u16*)(ws + 71565312);         // 128*512*2     = 131,072
    u16*  Wsb    = (u16*)(ws + 71696384);         // 256*256*2     = 131,072
    int*  rowoff = (int*)(ws + 71827456);         // 16384*9*4     = 589,824
    u16*  zpage  = (u16*)(ws + 72417280);         // 512 B zero page
    float* bc    = (float*)(ws + 72417792);       // 2048
    float* bp    = (float*)(ws + 72419840);       // 512

    prep<<<1024, 256, 0, stream>>>(stem_w,
                                   cls_conv_w, cls_conv_b, reg_conv_w, reg_conv_b,
                                   cls_pred_w, cls_pred_b, reg_pred_w, reg_pred_b,
                                   obj_pred_w, obj_pred_b,
                                   Wsb, Wc, Wf, bc, bp, zpage);
    rowptr_prep<<<576, 256, 0, stream>>>(idx, rowoff);
    transpose_x<<<800, 256, 0, stream>>>(x, xT);
    // K1: stem = silu(xT @ stem_w^T + b)  -> NHWC bf16 [51200][256]
    gemm_bt<0><<<dim3(400, 2), 256, 0, stream>>>(xT, Wsb, stem_b, stem, 256, 256, 256);
    // K3 fused gather+conv: feat = silu(gather(stem) @ Wc^T + bc)  [16384][512]
    gemm_conv<<<dim3(128, 4), 256, 0, stream>>>(stem, rowoff, zpage, Wc, bc, feat);
    // K4: out[n][p<85] = feat @ Wf^T + bp  (f32 store)
    gemm_bt<1><<<dim3(128, 1), 256, 0, stream>>>(feat, Wf, bp, out, 512, 85, 85);
}

// Round 4
// 117.760 us; speedup vs baseline: 1.2045x; 1.0354x over previous
//
#include <hip/hip_runtime.h>

typedef unsigned short u16;
typedef __attribute__((ext_vector_type(4))) float f32x4;
typedef __attribute__((ext_vector_type(8))) short s16x8;

#define BM 128
#define BN 128
#define BK 32

__device__ inline float bf2f(u16 u) {
    unsigned v = ((unsigned)u) << 16;
    return __builtin_bit_cast(float, v);
}
__device__ inline u16 f2bf(float f) {
    unsigned u = __builtin_bit_cast(unsigned, f);
    unsigned r = (u + 0x7FFFu + ((u >> 16) & 1u)) >> 16;
    return (u16)r;
}

typedef const __attribute__((address_space(1))) void* gptr_t;
typedef __attribute__((address_space(3))) void* lptr_t;
__device__ inline void gload16(const u16* gp, u16* lp) {
    __builtin_amdgcn_global_load_lds((gptr_t)gp, (lptr_t)lp, 16, 0, 0);
}

// ---------------- K0: x f32 [8][256][6400] -> xT bf16 [8][6400][256] ----------------
// LDS-staged so both global sides are coalesced. tile stride 258 elems:
// write bank = (l + c/2)&31 -> 2-way (free); read b128 uniform 4-deep.
__global__ __launch_bounds__(256) void transpose_x(const float* __restrict__ x,
                                                   u16* __restrict__ xT) {
    __shared__ u16 tile[64 * 258];
    int blk = blockIdx.x;              // 800 = 8 * 100
    int b = blk / 100, hw0 = (blk % 100) * 64;
    int t = threadIdx.x;
    int l = t & 63, w = t >> 6;
    const float* xb = x + (size_t)b * 256 * 6400 + hw0 + l;
#pragma unroll 4
    for (int k = 0; k < 64; ++k) {
        int c = w + k * 4;
        tile[l * 258 + c] = f2bf(xb[(size_t)c * 6400]);
    }
    __syncthreads();
    u16* outb = xT + ((size_t)b * 6400 + hw0) * 256;
#pragma unroll
    for (int i = 0; i < 8; ++i) {
        int hw = w * 16 + i * 2 + (l >> 5);
        int c = (l & 31) * 8;
        *(int4*)(outb + (size_t)hw * 256 + c) = *(const int4*)&tile[hw * 258 + c];
    }
}

// ---------------- prep: f32 weights -> bf16 (permuted) + f32 fused biases ----------------
__global__ __launch_bounds__(256) void prep(
    const float* __restrict__ stem_w,
    const float* __restrict__ cls_conv_w, const float* __restrict__ cls_conv_b,
    const float* __restrict__ reg_conv_w, const float* __restrict__ reg_conv_b,
    const float* __restrict__ cls_pred_w, const float* __restrict__ cls_pred_b,
    const float* __restrict__ reg_pred_w, const float* __restrict__ reg_pred_b,
    const float* __restrict__ obj_pred_w, const float* __restrict__ obj_pred_b,
    u16* __restrict__ Wsb, u16* __restrict__ Wc, u16* __restrict__ Wf,
    float* __restrict__ bc, float* __restrict__ bp, u16* __restrict__ zpage) {
    int i0 = blockIdx.x * 256 + threadIdx.x;
    int stride = gridDim.x * 256;
    for (int i = i0; i < 256 * 256; i += stride) Wsb[i] = f2bf(stem_w[i]);
    // Wc [512][2304] with k' = j*256 + c  <-  conv_w[o][c*9 + j]
    for (int i = i0; i < 512 * 2304; i += stride) {
        int o = i / 2304, kk = i % 2304;
        int j = kk >> 8, c = kk & 255;
        const float* src = (o < 256) ? (cls_conv_w + (size_t)o * 2304)
                                     : (reg_conv_w + (size_t)(o - 256) * 2304);
        Wc[i] = f2bf(src[c * 9 + j]);
    }
    // Wf [128][512]: rows 0-3 reg_pred (k 256..511), 4 obj, 5-84 cls (k 0..255), rest 0
    for (int i = i0; i < 128 * 512; i += stride) {
        int o = i >> 9, k = i & 511;
        float v = 0.f;
        if (o < 4)       { if (k >= 256) v = reg_pred_w[o * 256 + (k - 256)]; }
        else if (o == 4) { if (k >= 256) v = obj_pred_w[k - 256]; }
        else if (o < 85) { if (k < 256)  v = cls_pred_w[(o - 5) * 256 + k]; }
        Wf[i] = f2bf(v);
    }
    for (int i = i0; i < 512; i += stride)
        bc[i] = (i < 256) ? cls_conv_b[i] : reg_conv_b[i - 256];
    for (int i = i0; i < 128; i += stride) {
        float v = 0.f;
        if (i < 4) v = reg_pred_b[i];
        else if (i == 4) v = obj_pred_b[0];
        else if (i < 85) v = cls_pred_b[i - 5];
        bp[i] = v;
    }
    for (int i = i0; i < 256; i += stride) zpage[i] = 0;
}

// ---------------- rowoff: per (n, j) element offset into NHWC stem, or -1 ----------------
__global__ __launch_bounds__(256) void rowptr_prep(const int* __restrict__ idx,
                                                   int* __restrict__ rowoff) {
    int i = blockIdx.x * 256 + threadIdx.x;       // 147456 = 16384*9
    if (i >= 16384 * 9) return;
    int n = i / 9, j = i % 9;
    int b = idx[n * 3 + 0], y = idx[n * 3 + 1], x = idx[n * 3 + 2];
    int yy = y + j / 3 - 1;
    int xx = x + j % 3 - 1;
    rowoff[i] = ((unsigned)yy < 80u && (unsigned)xx < 80u)
                    ? (b * 6400 + yy * 80 + xx) * 256 : -1;
}

// ---------------- gemm_bt (verified): D[m,n] = epi(sum_k A[m,k]*B[n,k] + bias[n]) ----------
// EPI 0: silu, bf16 store, ldd = N.  EPI 1: plain, f32 store, only cols < storeN, ldd = storeN.
template <int EPI>
__global__ __launch_bounds__(256, 2) void gemm_bt(
    const u16* __restrict__ A, const u16* __restrict__ B,
    const float* __restrict__ bias, void* __restrict__ Dv,
    int K, int ldd, int storeN) {
    __shared__ __align__(16) u16 lA[BM * BK];
    __shared__ __align__(16) u16 lB[BN * BK];
    const int tid = threadIdx.x;
    const int lane = tid & 63;
    const int wid = tid >> 6;
    const int wm = wid >> 1, wn = wid & 1;
    const int m0 = blockIdx.x * BM;
    const int n0 = blockIdx.y * BN;

    const int srow = lane >> 2;
    const int scol = (lane & 3) * 8;
    const int arow = lane & 15;
    const int khalf = (lane >> 4) * 8;

    f32x4 acc[4][4] = {};

    for (int k0 = 0; k0 < K; k0 += BK) {
#pragma unroll
        for (int r = 0; r < 2; ++r) {
            int row = r * 64 + wid * 16 + srow;
            gload16(A + (size_t)(m0 + row) * K + k0 + scol, lA + r * 2048 + wid * 512);
            gload16(B + (size_t)(n0 + row) * K + k0 + scol, lB + r * 2048 + wid * 512);
        }
        __syncthreads();
        s16x8 af[4], bfr[4];
#pragma unroll
        for (int f = 0; f < 4; ++f) {
            af[f]  = *(const s16x8*)&lA[(wm * 64 + f * 16 + arow) * BK + khalf];
            bfr[f] = *(const s16x8*)&lB[(wn * 64 + f * 16 + arow) * BK + khalf];
        }
#pragma unroll
        for (int i = 0; i < 4; ++i)
#pragma unroll
            for (int j = 0; j < 4; ++j)
                acc[i][j] = __builtin_amdgcn_mfma_f32_16x16x32_bf16(af[i], bfr[j],
                                                                    acc[i][j], 0, 0, 0);
        __syncthreads();
    }

#pragma unroll
    for (int i = 0; i < 4; ++i) {
        int gr0 = m0 + wm * 64 + i * 16 + (lane >> 4) * 4;
#pragma unroll
        for (int j = 0; j < 4; ++j) {
            int gc = n0 + wn * 64 + j * 16 + (lane & 15);
            if (EPI == 1 && gc >= storeN) continue;
            float bb = bias[gc];
#pragma unroll
            for (int r = 0; r < 4; ++r) {
                float v = acc[i][j][r] + bb;
                if (EPI == 0) {
                    v = v / (1.0f + __expf(-v));
                    ((u16*)Dv)[(size_t)(gr0 + r) * ldd + gc] = f2bf(v);
                } else {
                    ((float*)Dv)[(size_t)(gr0 + r) * ldd + gc] = v;
                }
            }
        }
    }
}

// ---------------- K3 fused: feat = silu( gather(stem)[m,:] @ Wc^T + bc ) ----------------
// BM=128, BN=64, BK=64 -> grid (128,8) = 1024 blocks = 4 blocks/CU.
// A rows gathered from NHWC stem via rowoff; chunk XOR-swizzle both-sides (rule 21).
__global__ __launch_bounds__(256, 4) void gemm_conv(
    const u16* __restrict__ stem, const int* __restrict__ rowoff,
    const u16* __restrict__ zpage, const u16* __restrict__ B,
    const float* __restrict__ bias, u16* __restrict__ D) {
    __shared__ __align__(16) u16 lA[128 * 64];
    __shared__ __align__(16) u16 lB[64 * 64];
    const int tid = threadIdx.x;
    const int lane = tid & 63;
    const int wid = tid >> 6;
    const int wm = wid >> 1, wn = wid & 1;
    const int m0 = blockIdx.x * 128;
    const int n0 = blockIdx.y * 64;

    const int srw = lane >> 3;          // staging row within 8-row group (= row&7)
    const int cc  = lane & 7;           // staging chunk slot (16B units)
    const int arow = lane & 15;
    const int khi  = lane >> 4;         // 0..3

    f32x4 acc[4][2] = {};

    for (int k0 = 0; k0 < 2304; k0 += 64) {
        const int j  = k0 >> 8;         // kernel tap 0..8
        const int c0 = k0 & 255;        // channel base within tap
        const int gch = (cc ^ srw) * 8; // inverse-swizzled source chunk
#pragma unroll
        for (int r = 0; r < 4; ++r) {
            int row = r * 32 + wid * 8 + srw;          // 0..127 ; row&7 == srw
            int roff = rowoff[(m0 + row) * 9 + j];
            const u16* srcA = (roff < 0) ? (zpage + gch)
                                         : (stem + roff + c0 + gch);
            gload16(srcA, lA + (r * 32 + wid * 8) * 64);
        }
#pragma unroll
        for (int r = 0; r < 2; ++r) {
            int row = r * 32 + wid * 8 + srw;          // 0..63
            gload16(B + (size_t)(n0 + row) * 2304 + k0 + gch,
                    lB + (r * 32 + wid * 8) * 64);
        }
        __syncthreads();
        s16x8 af[2][4], bfr[2][2];
        const int sa = arow & 7;
#pragma unroll
        for (int f = 0; f < 4; ++f) {
            int ra = (wm * 64 + f * 16 + arow) * 64;
#pragma unroll
            for (int ks = 0; ks < 2; ++ks) {
                int q = ks * 4 + khi;
                af[ks][f] = *(const s16x8*)&lA[ra + ((q ^ sa) << 3)];
            }
        }
#pragma unroll
        for (int jj = 0; jj < 2; ++jj) {
            int rb = (wn * 32 + jj * 16 + arow) * 64;
#pragma unroll
            for (int ks = 0; ks < 2; ++ks) {
                int q = ks * 4 + khi;
                bfr[ks][jj] = *(const s16x8*)&lB[rb + ((q ^ sa) << 3)];
            }
        }
#pragma unroll
        for (int ks = 0; ks < 2; ++ks)
#pragma unroll
            for (int i = 0; i < 4; ++i)
#pragma unroll
                for (int jj = 0; jj < 2; ++jj)
                    acc[i][jj] = __builtin_amdgcn_mfma_f32_16x16x32_bf16(
                        af[ks][i], bfr[ks][jj], acc[i][jj], 0, 0, 0);
        __syncthreads();
    }

#pragma unroll
    for (int i = 0; i < 4; ++i) {
        int gr0 = m0 + wm * 64 + i * 16 + khi * 4;
#pragma unroll
        for (int jj = 0; jj < 2; ++jj) {
            int gc = n0 + wn * 32 + jj * 16 + arow;
            float bb = bias[gc];
#pragma unroll
            for (int r = 0; r < 4; ++r) {
                float v = acc[i][jj][r] + bb;
                v = v / (1.0f + __expf(-v));
                D[(size_t)(gr0 + r) * 512 + gc] = f2bf(v);
            }
        }
    }
}

extern "C" void kernel_launch(void* const* d_in, const int* in_sizes, int n_in,
                              void* d_out, int out_size, void* d_ws, size_t ws_size,
                              hipStream_t stream) {
    const float* x          = (const float*)d_in[0];
    const int*   idx        = (const int*)d_in[1];
    const float* stem_w     = (const float*)d_in[2];
    const float* stem_b     = (const float*)d_in[3];
    const float* cls_conv_w = (const float*)d_in[4];
    const float* cls_conv_b = (const float*)d_in[5];
    const float* reg_conv_w = (const float*)d_in[6];
    const float* reg_conv_b = (const float*)d_in[7];
    const float* cls_pred_w = (const float*)d_in[8];
    const float* cls_pred_b = (const float*)d_in[9];
    const float* reg_pred_w = (const float*)d_in[10];
    const float* reg_pred_b = (const float*)d_in[11];
    const float* obj_pred_w = (const float*)d_in[12];
    const float* obj_pred_b = (const float*)d_in[13];
    float* out = (float*)d_out;
    char* ws = (char*)d_ws;

    // ws layout (bytes), all 16B-aligned; total ~72.4 MB
    u16*  xT     = (u16*)(ws);                    // 8*6400*256*2  = 26,214,400
    u16*  stem   = (u16*)(ws + 26214400);         // 26,214,400 (NHWC bf16)
    u16*  feat   = (u16*)(ws + 52428800);         // 16384*512*2   = 16,777,216
    u16*  Wc     = (u16*)(ws + 69206016);         // 512*2304*2    = 2,359,296
    u16*  Wf     = (u16*)(ws + 71565312);         // 128*512*2     = 131,072
    u16*  Wsb    = (u16*)(ws + 71696384);         // 256*256*2     = 131,072
    int*  rowoff = (int*)(ws + 71827456);         // 16384*9*4     = 589,824
    u16*  zpage  = (u16*)(ws + 72417280);         // 512 B zero page
    float* bc    = (float*)(ws + 72417792);       // 2048
    float* bp    = (float*)(ws + 72419840);       // 512

    prep<<<1024, 256, 0, stream>>>(stem_w,
                                   cls_conv_w, cls_conv_b, reg_conv_w, reg_conv_b,
                                   cls_pred_w, cls_pred_b, reg_pred_w, reg_pred_b,
                                   obj_pred_w, obj_pred_b,
                                   Wsb, Wc, Wf, bc, bp, zpage);
    rowptr_prep<<<576, 256, 0, stream>>>(idx, rowoff);
    transpose_x<<<800, 256, 0, stream>>>(x, xT);
    // K1: stem = silu(xT @ stem_w^T + b)  -> NHWC bf16 [51200][256]
    gemm_bt<0><<<dim3(400, 2), 256, 0, stream>>>(xT, Wsb, stem_b, stem, 256, 256, 256);
    // K3 fused gather+conv: feat = silu(gather(stem) @ Wc^T + bc)  [16384][512]
    gemm_conv<<<dim3(128, 8), 256, 0, stream>>>(stem, rowoff, zpage, Wc, bc, feat);
    // K4: out[n][p<85] = feat @ Wf^T + bp  (f32 store)
    gemm_bt<1><<<dim3(128, 1), 256, 0, stream>>>(feat, Wf, bp, out, 512, 85, 85);
}